// Round 13
// baseline (269.001 us; speedup 1.0000x reference)
//
#include <hip/hip_runtime.h>
#include <stdint.h>

#define N_NODES   50000
#define N_EDGES   400000
#define IN_FEATS  16
#define HIDDEN    32
#define K1        128      // EDGE_MLP_HID
#define NOUT      512      // IN_FEATS*HIDDEN
#define N_CLS     100000
#define CAP       40       // max degree slots (Poisson(8): P(deg>40) ~ 0)
#define TILE_E    128
#define FUSED_BLOCKS (N_EDGES / TILE_E)   // 3125

typedef float  f32x4  __attribute__((ext_vector_type(4)));
typedef __bf16 bf16x8 __attribute__((ext_vector_type(8)));

__device__ __forceinline__ unsigned short f32_bf16(float f) {
    union { float f; uint32_t u; } c; c.f = f;
    uint32_t r = c.u + 0x7fffu + ((c.u >> 16) & 1u);
    return (unsigned short)(r >> 16);
}

// async global->LDS, 16B per lane; LDS dest is wave-uniform base + lane*16
__device__ __forceinline__ void gload_lds16(const unsigned short* g, unsigned short* l) {
    __builtin_amdgcn_global_load_lds(
        (const __attribute__((address_space(1))) unsigned int*)(g),
        (__attribute__((address_space(3))) unsigned int*)(l),
        16, 0, 0);
}

// ---- merged prep: weights transpose/convert + dst bucketing ----
// w2ts: W2 [128,512] -> bf16 [512,128], PRE-SWIZZLED k ^= (n&15)<<3 (R10/R11-verified:
//       cuts ds_read_b128 bank conflicts ~6x; rule #21 source-side swizzle).
// w1t:  W1 [16,128] -> bf16 [128,32] (K padded 16->32), linear.
__global__ void prep_and_slots(const float* __restrict__ w2, const float* __restrict__ w1,
                               const int* __restrict__ dst,
                               unsigned short* __restrict__ w2ts, unsigned short* __restrict__ w1t,
                               int* __restrict__ cursor, int* __restrict__ slots) {
    int gid = blockIdx.x * 256 + threadIdx.x;
    if (gid < NOUT * K1) {
        int n = gid >> 7, k = gid & 127;
        w2ts[n * 128 + (k ^ ((n & 15) << 3))] = f32_bf16(w2[k * 512 + n]);
    } else if (gid < NOUT * K1 + 4096) {
        int t = gid - NOUT * K1;
        int n = t >> 5, k = t & 31;
        w1t[n * 32 + k] = (k < 16) ? f32_bf16(w1[k * 128 + n]) : (unsigned short)0;
    }
    if (gid < N_EDGES) {
        int d = dst[gid];
        int pos = atomicAdd(&cursor[d], 1);
        if (pos < CAP) slots[d * CAP + pos] = gid;
    }
}

// ---- fused: edge MLP (MFMA, swapped operands) + per-edge matvec ----
// R11-verified structure: 128-edge tile, 4 waves; wave w owns edges [w*32, w*32+32),
// sweeps all 512 cols in 8 x 64-col chunks, double-buffered in the dead relu1 LDS
// region (32KB total). Only delta vs R11: min-waves 4 -> 5 (5 blocks/CU fit 160KB LDS
// exactly; VGPR 64 << 102 cap).
__global__ __launch_bounds__(256, 5) void fused_msg(
    const float* __restrict__ nf, const float* __restrict__ ef,
    const int* __restrict__ src,
    const unsigned short* __restrict__ w1t, const float* __restrict__ b1,
    const unsigned short* __restrict__ w2ts, const float* __restrict__ b2,
    float* __restrict__ msg)
{
    __shared__ __align__(16) unsigned short sAmem[128 * 128]; // 32KB: relu1, then B buf0|buf1

    const int tid  = threadIdx.x;
    const int lane = tid & 63;
    const int w    = tid >> 6;      // wave 0..3
    const int l15  = lane & 15;
    const int lg   = lane >> 4;     // 0..3
    const int key  = (l15 & 7) << 3;   // relu1 (sA) swizzle key (write+read paired)
    const int key2 = l15 << 3;         // B swizzle key, full 4-bit (matches w2ts pre-swizzle)
    const int e0   = blockIdx.x * TILE_E;

    unsigned short* buf0 = sAmem;            // 16KB (64 rows x 128)
    unsigned short* buf1 = sAmem + 8192;     // 16KB

    // stage 64-col chunk cc (8192 elems) linearly: 4 waves x 4 calls x 1KB
    // (chunk base row cc*64 is a multiple of 16, so local row&15 == global n&15)
    auto stage = [&](int cc, unsigned short* buf) {
        #pragma unroll
        for (int i = 0; i < 4; ++i)
            gload_lds16(&w2ts[cc * 8192 + (w * 4 + i) * 512 + lane * 8],
                        &buf[(w * 4 + i) * 512]);
    };

    // per-lane edges for P2
    const int ea = e0 + w * 32 + l15;
    const int eb = ea + 16;
    const int sa0 = src[ea];
    const int sa1 = src[eb];

    // ---------- P1: relu1[128][128] via 64 MFMA; wave w owns n1-tiles {2w, 2w+1} ----------
    {
        bf16x8 w1f0 = *reinterpret_cast<const bf16x8*>(&w1t[((2 * w) * 16 + l15) * 32 + lg * 8]);
        bf16x8 w1f1 = *reinterpret_cast<const bf16x8*>(&w1t[((2 * w + 1) * 16 + l15) * 32 + lg * 8]);
        float4 q0 = *reinterpret_cast<const float4*>(&b1[(2 * w) * 16 + lg * 4]);
        float4 q1 = *reinterpret_cast<const float4*>(&b1[(2 * w + 1) * 16 + lg * 4]);
        #pragma unroll
        for (int et = 0; et < 8; ++et) {
            int e = e0 + et * 16 + l15;
            bf16x8 aef;
            if (lg < 2) {
                float4 f0 = *reinterpret_cast<const float4*>(&ef[e * 16 + lg * 8]);
                float4 f1 = *reinterpret_cast<const float4*>(&ef[e * 16 + lg * 8 + 4]);
                unsigned short t8[8] = { f32_bf16(f0.x), f32_bf16(f0.y), f32_bf16(f0.z), f32_bf16(f0.w),
                                         f32_bf16(f1.x), f32_bf16(f1.y), f32_bf16(f1.z), f32_bf16(f1.w) };
                aef = *reinterpret_cast<const bf16x8*>(t8);
            } else {
                aef = bf16x8(0);   // K-pad (k >= 16)
            }
            int le = et * 16 + l15;
            f32x4 c0 = { q0.x, q0.y, q0.z, q0.w };
            c0 = __builtin_amdgcn_mfma_f32_16x16x32_bf16(w1f0, aef, c0, 0, 0, 0);
            uint32_t u0 = (uint32_t)f32_bf16(fmaxf(c0[0], 0.f)) | ((uint32_t)f32_bf16(fmaxf(c0[1], 0.f)) << 16);
            uint32_t u1 = (uint32_t)f32_bf16(fmaxf(c0[2], 0.f)) | ((uint32_t)f32_bf16(fmaxf(c0[3], 0.f)) << 16);
            uint2 pk0 = { u0, u1 };
            *reinterpret_cast<uint2*>(&sAmem[le * 128 + (((2 * w) * 16 + lg * 4) ^ key)]) = pk0;

            f32x4 c1 = { q1.x, q1.y, q1.z, q1.w };
            c1 = __builtin_amdgcn_mfma_f32_16x16x32_bf16(w1f1, aef, c1, 0, 0, 0);
            uint32_t u2 = (uint32_t)f32_bf16(fmaxf(c1[0], 0.f)) | ((uint32_t)f32_bf16(fmaxf(c1[1], 0.f)) << 16);
            uint32_t u3 = (uint32_t)f32_bf16(fmaxf(c1[2], 0.f)) | ((uint32_t)f32_bf16(fmaxf(c1[3], 0.f)) << 16);
            uint2 pk1 = { u2, u3 };
            *reinterpret_cast<uint2*>(&sAmem[le * 128 + (((2 * w + 1) * 16 + lg * 4) ^ key)]) = pk1;
        }
    }
    __syncthreads();   // relu1 visible

    // ---- A fragments for this wave's 32 edges (regs for all 8 chunks) ----
    bf16x8 aF[2][4];
    #pragma unroll
    for (int et = 0; et < 2; ++et) {
        int le = w * 32 + et * 16 + l15;
        #pragma unroll
        for (int kb = 0; kb < 4; ++kb)
            aF[et][kb] = *reinterpret_cast<const bf16x8*>(
                &sAmem[le * 128 + ((kb * 32 + lg * 8) ^ key)]);
    }
    __syncthreads();   // all waves done reading relu1 -> sAmem reusable as B buffers

    stage(0, buf0);
    stage(1, buf1);
    __syncthreads();   // vmcnt drained: chunks 0,1 resident

    float msgv[2][8];
    #pragma unroll
    for (int et = 0; et < 2; ++et)
        #pragma unroll
        for (int q = 0; q < 8; ++q) msgv[et][q] = 0.f;

    // ---------- P2: 8 x 64-col chunks, double-buffered, stage-ahead-by-2 ----------
    #pragma unroll 1
    for (int c = 0; c < 8; ++c) {
        const unsigned short* sCur = (c & 1) ? buf1 : buf0;

        float2 xw0 = *reinterpret_cast<const float2*>(&nf[sa0 * 16 + c * 2]);
        float2 xw1 = *reinterpret_cast<const float2*>(&nf[sa1 * 16 + c * 2]);

        #pragma unroll
        for (int f = 0; f < 4; ++f) {
            int n = f * 16 + l15;                 // local row; row&15 == l15
            bf16x8 bw[4];
            #pragma unroll
            for (int kb = 0; kb < 4; ++kb)
                bw[kb] = *reinterpret_cast<const bf16x8*>(
                    &sCur[n * 128 + ((kb * 32 + lg * 8) ^ key2)]);
            float4 b2q = *reinterpret_cast<const float4*>(&b2[c * 64 + f * 16 + lg * 4]);
            f32x4 a0 = { b2q.x, b2q.y, b2q.z, b2q.w };
            f32x4 a1 = a0;
            #pragma unroll
            for (int kb = 0; kb < 4; ++kb) {
                a0 = __builtin_amdgcn_mfma_f32_16x16x32_bf16(bw[kb], aF[0][kb], a0, 0, 0, 0);
                a1 = __builtin_amdgcn_mfma_f32_16x16x32_bf16(bw[kb], aF[1][kb], a1, 0, 0, 0);
            }
            // global n = c*64 + f*16 + lg*4 + r ; i = c*2 + (f>>1) ; h = (f&1)*16 + lg*4 + r
            const float x0 = (f >> 1) ? xw0.y : xw0.x;
            const float x1 = (f >> 1) ? xw1.y : xw1.x;
            const int s = (f & 1) * 4;
            #pragma unroll
            for (int r = 0; r < 4; ++r) {
                msgv[0][s + r] += x0 * a0[r];
                msgv[1][s + r] += x1 * a1[r];
            }
        }

        if (c < 7) {
            __syncthreads();                       // all waves done reading sCur
            if (c + 2 < 8) stage(c + 2, (c & 1) ? buf1 : buf0);  // overlaps compute(c+1)
        }
    }

    // ---------- store msg: lane owns edges ea/eb, h-slice lg*4 + {0,16} ----------
    #pragma unroll
    for (int et = 0; et < 2; ++et) {
        int e = et ? eb : ea;
        #pragma unroll
        for (int half = 0; half < 2; ++half) {
            float4 o = { msgv[et][half * 4 + 0], msgv[et][half * 4 + 1],
                         msgv[et][half * 4 + 2], msgv[et][half * 4 + 3] };
            *reinterpret_cast<float4*>(&msg[e * 32 + half * 16 + lg * 4]) = o;
        }
    }
}

// ---- aggregate: h[n][q*4..q*4+3] = relu(mean over slot edges of msg + conv_b), float4 ----
__global__ __launch_bounds__(256) void aggregate_h(
    const float* __restrict__ msg, const int* __restrict__ cursor,
    const int* __restrict__ slots, const float* __restrict__ conv_b,
    float* __restrict__ h)
{
    int t = blockIdx.x * 256 + threadIdx.x;
    int n = t >> 3;
    if (n >= N_NODES) return;
    int q = t & 7;                              // h-quad index
    int d = cursor[n];
    int dm = d < CAP ? d : CAP;
    const int* row = &slots[n * CAP];
    float4 s = { 0.f, 0.f, 0.f, 0.f };
    int j = 0;
    for (; j + 2 <= dm; j += 2) {
        int ee0 = row[j], ee1 = row[j + 1];
        float4 v0 = *reinterpret_cast<const float4*>(&msg[ee0 * 32 + q * 4]);
        float4 v1 = *reinterpret_cast<const float4*>(&msg[ee1 * 32 + q * 4]);
        s.x += v0.x + v1.x; s.y += v0.y + v1.y; s.z += v0.z + v1.z; s.w += v0.w + v1.w;
    }
    if (j < dm) {
        float4 v = *reinterpret_cast<const float4*>(&msg[row[j] * 32 + q * 4]);
        s.x += v.x; s.y += v.y; s.z += v.z; s.w += v.w;
    }
    float inv = 1.0f / fmaxf((float)d, 1.f);
    float4 cb = *reinterpret_cast<const float4*>(&conv_b[q * 4]);
    float4 o;
    o.x = fmaxf(s.x * inv + cb.x, 0.f);
    o.y = fmaxf(s.y * inv + cb.y, 0.f);
    o.z = fmaxf(s.z * inv + cb.z, 0.f);
    o.w = fmaxf(s.w * inv + cb.w, 0.f);
    *reinterpret_cast<float4*>(&h[n * 32 + q * 4]) = o;
}

// ---- classifier: 32 edges per 256-thread block ----
__global__ __launch_bounds__(256) void classifier(
    const float* __restrict__ h, const float* __restrict__ ef,
    const int* __restrict__ src, const int* __restrict__ dst, const int* __restrict__ eidx,
    const float* __restrict__ w1, const float* __restrict__ b1,
    const float* __restrict__ w2, const float* __restrict__ b2, float* __restrict__ out)
{
    __shared__ float sIn[32][84];
    __shared__ float sW1[80 * 32];
    __shared__ float sHid[32][36];
    __shared__ int   sE[32 * 3];
    int tid = threadIdx.x;
    int eb  = blockIdx.x * 32;

    for (int i = tid; i < 640; i += 256)
        *reinterpret_cast<float4*>(&sW1[i * 4]) = *reinterpret_cast<const float4*>(&w1[i * 4]);
    if (tid < 32) {
        int ei = eidx[eb + tid];
        sE[tid * 3 + 0] = ei;
        sE[tid * 3 + 1] = src[ei];
        sE[tid * 3 + 2] = dst[ei];
    }
    __syncthreads();
    {
        int e = tid >> 3, l8 = tid & 7;
        int ei = sE[e * 3 + 0], sn = sE[e * 3 + 1], dn = sE[e * 3 + 2];
        #pragma unroll
        for (int j = 0; j < 10; ++j) {
            int c = l8 + j * 8;
            float v;
            if (c < 32)      v = h[sn * 32 + c];
            else if (c < 64) v = h[dn * 32 + (c - 32)];
            else             v = ef[ei * 16 + (c - 64)];
            sIn[e][c] = v;
        }
    }
    __syncthreads();
    {
        int e = tid >> 3, j0 = (tid & 7) * 4;
        float4 acc = *reinterpret_cast<const float4*>(&b1[j0]);
        #pragma unroll 8
        for (int k = 0; k < 80; ++k) {
            float x = sIn[e][k];
            float4 wv = *reinterpret_cast<const float4*>(&sW1[k * 32 + j0]);
            acc.x += x * wv.x; acc.y += x * wv.y; acc.z += x * wv.z; acc.w += x * wv.w;
        }
        sHid[e][j0 + 0] = fmaxf(acc.x, 0.f);
        sHid[e][j0 + 1] = fmaxf(acc.y, 0.f);
        sHid[e][j0 + 2] = fmaxf(acc.z, 0.f);
        sHid[e][j0 + 3] = fmaxf(acc.w, 0.f);
    }
    __syncthreads();
    if (tid < 64) {
        int e = tid >> 1, o = tid & 1;
        float acc = b2[o];
        #pragma unroll
        for (int j = 0; j < 32; ++j) acc += sHid[e][j] * w2[j * 2 + o];
        out[(eb + e) * 2 + o] = acc;
    }
}

extern "C" void kernel_launch(void* const* d_in, const int* in_sizes, int n_in,
                              void* d_out, int out_size, void* d_ws, size_t ws_size,
                              hipStream_t stream) {
    const float* nf     = (const float*)d_in[0];
    const float* ef     = (const float*)d_in[1];
    const int*   src    = (const int*)d_in[2];
    const int*   dst    = (const int*)d_in[3];
    const int*   eidx   = (const int*)d_in[4];
    const float* en_w1  = (const float*)d_in[5];
    const float* en_b1  = (const float*)d_in[6];
    const float* en_w2  = (const float*)d_in[7];
    const float* en_b2  = (const float*)d_in[8];
    const float* conv_b = (const float*)d_in[9];
    const float* cls_w1 = (const float*)d_in[10];
    const float* cls_b1 = (const float*)d_in[11];
    const float* cls_w2 = (const float*)d_in[12];
    const float* cls_b2 = (const float*)d_in[13];
    float* out = (float*)d_out;

    char* ws = (char*)d_ws;
    unsigned short* w2ts   = (unsigned short*)(ws);                 // 131,072 B (pre-swizzled, n&15 key)
    unsigned short* w1t    = (unsigned short*)(ws + 131072);        //   8,192 B
    int*            cursor = (int*)(ws + 139264);                   // 200,000 B
    int*            slots  = (int*)(ws + 339264);                   // 8,000,000 B
    float*          msgb   = (float*)(ws + 8339264);                // 51,200,000 B
    float*          h      = (float*)(ws + 59539264);               // 6,400,000 B

    hipMemsetAsync(cursor, 0, N_NODES * sizeof(int), stream);
    prep_and_slots<<<(N_EDGES + 255) / 256, 256, 0, stream>>>(en_w2, en_w1, dst, w2ts, w1t, cursor, slots);
    fused_msg<<<FUSED_BLOCKS, 256, 0, stream>>>(nf, ef, src, w1t, en_b1, w2ts, en_b2, msgb);
    aggregate_h<<<(N_NODES * 8 + 255) / 256, 256, 0, stream>>>(msgb, cursor, slots, conv_b, h);
    classifier<<<N_CLS / 32, 256, 0, stream>>>(h, ef, src, dst, eidx, cls_w1, cls_b1, cls_w2, cls_b2, out);
}

// Round 14
// 140.296 us; speedup vs baseline: 1.9174x; 1.9174x over previous
//
#include <hip/hip_runtime.h>
#include <stdint.h>

#define N_NODES   50000
#define N_EDGES   400000
#define IN_FEATS  16
#define HIDDEN    32
#define K1        128      // EDGE_MLP_HID
#define NOUT      512      // IN_FEATS*HIDDEN
#define N_CLS     100000
#define CAP       40       // max degree slots (Poisson(8): P(deg>40) ~ 0)
#define TILE_E    128
#define FUSED_BLOCKS (N_EDGES / TILE_E)   // 3125

typedef float  f32x4  __attribute__((ext_vector_type(4)));
typedef __bf16 bf16x8 __attribute__((ext_vector_type(8)));

__device__ __forceinline__ unsigned short f32_bf16(float f) {
    union { float f; uint32_t u; } c; c.f = f;
    uint32_t r = c.u + 0x7fffu + ((c.u >> 16) & 1u);
    return (unsigned short)(r >> 16);
}

// async global->LDS, 16B per lane; LDS dest is wave-uniform base + lane*16
__device__ __forceinline__ void gload_lds16(const unsigned short* g, unsigned short* l) {
    __builtin_amdgcn_global_load_lds(
        (const __attribute__((address_space(1))) unsigned int*)(g),
        (__attribute__((address_space(3))) unsigned int*)(l),
        16, 0, 0);
}

// ---- merged prep: weights transpose/convert + dst bucketing ----
// w2ts: W2 [128,512] -> bf16 [512,128], PRE-SWIZZLED k ^= (n&15)<<3 (R10/R11-verified:
//       cuts ds_read_b128 bank conflicts ~6x; rule #21 source-side swizzle).
// w1t:  W1 [16,128] -> bf16 [128,32] (K padded 16->32), linear.
__global__ void prep_and_slots(const float* __restrict__ w2, const float* __restrict__ w1,
                               const int* __restrict__ dst,
                               unsigned short* __restrict__ w2ts, unsigned short* __restrict__ w1t,
                               int* __restrict__ cursor, int* __restrict__ slots) {
    int gid = blockIdx.x * 256 + threadIdx.x;
    if (gid < NOUT * K1) {
        int n = gid >> 7, k = gid & 127;
        w2ts[n * 128 + (k ^ ((n & 15) << 3))] = f32_bf16(w2[k * 512 + n]);
    } else if (gid < NOUT * K1 + 4096) {
        int t = gid - NOUT * K1;
        int n = t >> 5, k = t & 31;
        w1t[n * 32 + k] = (k < 16) ? f32_bf16(w1[k * 128 + n]) : (unsigned short)0;
    }
    if (gid < N_EDGES) {
        int d = dst[gid];
        int pos = atomicAdd(&cursor[d], 1);
        if (pos < CAP) slots[d * CAP + pos] = gid;
    }
}

// ---- fused: edge MLP (MFMA, swapped operands) + per-edge matvec ----
// R11-verified structure (best known: ~86us, VGPR 64, zero spill): 128-edge tile,
// 4 waves; wave w owns edges [w*32, w*32+32), sweeps all 512 cols in 8 x 64-col
// chunks, double-buffered in the dead relu1 LDS region (32KB total).
// NOTE: min-waves MUST stay 4 — (256,5) in R13 forced VGPR 48 and spilled ~700MB
// of scratch (fused 86 -> 227us). Never constrain VGPR below ~64 on this kernel.
__global__ __launch_bounds__(256, 4) void fused_msg(
    const float* __restrict__ nf, const float* __restrict__ ef,
    const int* __restrict__ src,
    const unsigned short* __restrict__ w1t, const float* __restrict__ b1,
    const unsigned short* __restrict__ w2ts, const float* __restrict__ b2,
    float* __restrict__ msg)
{
    __shared__ __align__(16) unsigned short sAmem[128 * 128]; // 32KB: relu1, then B buf0|buf1

    const int tid  = threadIdx.x;
    const int lane = tid & 63;
    const int w    = tid >> 6;      // wave 0..3
    const int l15  = lane & 15;
    const int lg   = lane >> 4;     // 0..3
    const int key  = (l15 & 7) << 3;   // relu1 (sA) swizzle key (write+read paired)
    const int key2 = l15 << 3;         // B swizzle key, full 4-bit (matches w2ts pre-swizzle)
    const int e0   = blockIdx.x * TILE_E;

    unsigned short* buf0 = sAmem;            // 16KB (64 rows x 128)
    unsigned short* buf1 = sAmem + 8192;     // 16KB

    // stage 64-col chunk cc (8192 elems) linearly: 4 waves x 4 calls x 1KB
    // (chunk base row cc*64 is a multiple of 16, so local row&15 == global n&15)
    auto stage = [&](int cc, unsigned short* buf) {
        #pragma unroll
        for (int i = 0; i < 4; ++i)
            gload_lds16(&w2ts[cc * 8192 + (w * 4 + i) * 512 + lane * 8],
                        &buf[(w * 4 + i) * 512]);
    };

    // per-lane edges for P2
    const int ea = e0 + w * 32 + l15;
    const int eb = ea + 16;
    const int sa0 = src[ea];
    const int sa1 = src[eb];

    // ---------- P1: relu1[128][128] via 64 MFMA; wave w owns n1-tiles {2w, 2w+1} ----------
    {
        bf16x8 w1f0 = *reinterpret_cast<const bf16x8*>(&w1t[((2 * w) * 16 + l15) * 32 + lg * 8]);
        bf16x8 w1f1 = *reinterpret_cast<const bf16x8*>(&w1t[((2 * w + 1) * 16 + l15) * 32 + lg * 8]);
        float4 q0 = *reinterpret_cast<const float4*>(&b1[(2 * w) * 16 + lg * 4]);
        float4 q1 = *reinterpret_cast<const float4*>(&b1[(2 * w + 1) * 16 + lg * 4]);
        #pragma unroll
        for (int et = 0; et < 8; ++et) {
            int e = e0 + et * 16 + l15;
            bf16x8 aef;
            if (lg < 2) {
                float4 f0 = *reinterpret_cast<const float4*>(&ef[e * 16 + lg * 8]);
                float4 f1 = *reinterpret_cast<const float4*>(&ef[e * 16 + lg * 8 + 4]);
                unsigned short t8[8] = { f32_bf16(f0.x), f32_bf16(f0.y), f32_bf16(f0.z), f32_bf16(f0.w),
                                         f32_bf16(f1.x), f32_bf16(f1.y), f32_bf16(f1.z), f32_bf16(f1.w) };
                aef = *reinterpret_cast<const bf16x8*>(t8);
            } else {
                aef = bf16x8(0);   // K-pad (k >= 16)
            }
            int le = et * 16 + l15;
            f32x4 c0 = { q0.x, q0.y, q0.z, q0.w };
            c0 = __builtin_amdgcn_mfma_f32_16x16x32_bf16(w1f0, aef, c0, 0, 0, 0);
            uint32_t u0 = (uint32_t)f32_bf16(fmaxf(c0[0], 0.f)) | ((uint32_t)f32_bf16(fmaxf(c0[1], 0.f)) << 16);
            uint32_t u1 = (uint32_t)f32_bf16(fmaxf(c0[2], 0.f)) | ((uint32_t)f32_bf16(fmaxf(c0[3], 0.f)) << 16);
            uint2 pk0 = { u0, u1 };
            *reinterpret_cast<uint2*>(&sAmem[le * 128 + (((2 * w) * 16 + lg * 4) ^ key)]) = pk0;

            f32x4 c1 = { q1.x, q1.y, q1.z, q1.w };
            c1 = __builtin_amdgcn_mfma_f32_16x16x32_bf16(w1f1, aef, c1, 0, 0, 0);
            uint32_t u2 = (uint32_t)f32_bf16(fmaxf(c1[0], 0.f)) | ((uint32_t)f32_bf16(fmaxf(c1[1], 0.f)) << 16);
            uint32_t u3 = (uint32_t)f32_bf16(fmaxf(c1[2], 0.f)) | ((uint32_t)f32_bf16(fmaxf(c1[3], 0.f)) << 16);
            uint2 pk1 = { u2, u3 };
            *reinterpret_cast<uint2*>(&sAmem[le * 128 + (((2 * w + 1) * 16 + lg * 4) ^ key)]) = pk1;
        }
    }
    __syncthreads();   // relu1 visible

    // ---- A fragments for this wave's 32 edges (regs for all 8 chunks) ----
    bf16x8 aF[2][4];
    #pragma unroll
    for (int et = 0; et < 2; ++et) {
        int le = w * 32 + et * 16 + l15;
        #pragma unroll
        for (int kb = 0; kb < 4; ++kb)
            aF[et][kb] = *reinterpret_cast<const bf16x8*>(
                &sAmem[le * 128 + ((kb * 32 + lg * 8) ^ key)]);
    }
    __syncthreads();   // all waves done reading relu1 -> sAmem reusable as B buffers

    stage(0, buf0);
    stage(1, buf1);
    __syncthreads();   // vmcnt drained: chunks 0,1 resident

    float msgv[2][8];
    #pragma unroll
    for (int et = 0; et < 2; ++et)
        #pragma unroll
        for (int q = 0; q < 8; ++q) msgv[et][q] = 0.f;

    // ---------- P2: 8 x 64-col chunks, double-buffered, stage-ahead-by-2 ----------
    #pragma unroll 1
    for (int c = 0; c < 8; ++c) {
        const unsigned short* sCur = (c & 1) ? buf1 : buf0;

        float2 xw0 = *reinterpret_cast<const float2*>(&nf[sa0 * 16 + c * 2]);
        float2 xw1 = *reinterpret_cast<const float2*>(&nf[sa1 * 16 + c * 2]);

        #pragma unroll
        for (int f = 0; f < 4; ++f) {
            int n = f * 16 + l15;                 // local row; row&15 == l15
            bf16x8 bw[4];
            #pragma unroll
            for (int kb = 0; kb < 4; ++kb)
                bw[kb] = *reinterpret_cast<const bf16x8*>(
                    &sCur[n * 128 + ((kb * 32 + lg * 8) ^ key2)]);
            float4 b2q = *reinterpret_cast<const float4*>(&b2[c * 64 + f * 16 + lg * 4]);
            f32x4 a0 = { b2q.x, b2q.y, b2q.z, b2q.w };
            f32x4 a1 = a0;
            #pragma unroll
            for (int kb = 0; kb < 4; ++kb) {
                a0 = __builtin_amdgcn_mfma_f32_16x16x32_bf16(bw[kb], aF[0][kb], a0, 0, 0, 0);
                a1 = __builtin_amdgcn_mfma_f32_16x16x32_bf16(bw[kb], aF[1][kb], a1, 0, 0, 0);
            }
            // global n = c*64 + f*16 + lg*4 + r ; i = c*2 + (f>>1) ; h = (f&1)*16 + lg*4 + r
            const float x0 = (f >> 1) ? xw0.y : xw0.x;
            const float x1 = (f >> 1) ? xw1.y : xw1.x;
            const int s = (f & 1) * 4;
            #pragma unroll
            for (int r = 0; r < 4; ++r) {
                msgv[0][s + r] += x0 * a0[r];
                msgv[1][s + r] += x1 * a1[r];
            }
        }

        if (c < 7) {
            __syncthreads();                       // all waves done reading sCur
            if (c + 2 < 8) stage(c + 2, (c & 1) ? buf1 : buf0);  // overlaps compute(c+1)
        }
    }

    // ---------- store msg: lane owns edges ea/eb, h-slice lg*4 + {0,16} ----------
    #pragma unroll
    for (int et = 0; et < 2; ++et) {
        int e = et ? eb : ea;
        #pragma unroll
        for (int half = 0; half < 2; ++half) {
            float4 o = { msgv[et][half * 4 + 0], msgv[et][half * 4 + 1],
                         msgv[et][half * 4 + 2], msgv[et][half * 4 + 3] };
            *reinterpret_cast<float4*>(&msg[e * 32 + half * 16 + lg * 4]) = o;
        }
    }
}

// ---- aggregate: h[n][q*4..q*4+3] = relu(mean over slot edges of msg + conv_b), float4 ----
// (R13-verified correct: absmax unchanged)
__global__ __launch_bounds__(256) void aggregate_h(
    const float* __restrict__ msg, const int* __restrict__ cursor,
    const int* __restrict__ slots, const float* __restrict__ conv_b,
    float* __restrict__ h)
{
    int t = blockIdx.x * 256 + threadIdx.x;
    int n = t >> 3;
    if (n >= N_NODES) return;
    int q = t & 7;                              // h-quad index
    int d = cursor[n];
    int dm = d < CAP ? d : CAP;
    const int* row = &slots[n * CAP];
    float4 s = { 0.f, 0.f, 0.f, 0.f };
    int j = 0;
    for (; j + 2 <= dm; j += 2) {
        int ee0 = row[j], ee1 = row[j + 1];
        float4 v0 = *reinterpret_cast<const float4*>(&msg[ee0 * 32 + q * 4]);
        float4 v1 = *reinterpret_cast<const float4*>(&msg[ee1 * 32 + q * 4]);
        s.x += v0.x + v1.x; s.y += v0.y + v1.y; s.z += v0.z + v1.z; s.w += v0.w + v1.w;
    }
    if (j < dm) {
        float4 v = *reinterpret_cast<const float4*>(&msg[row[j] * 32 + q * 4]);
        s.x += v.x; s.y += v.y; s.z += v.z; s.w += v.w;
    }
    float inv = 1.0f / fmaxf((float)d, 1.f);
    float4 cb = *reinterpret_cast<const float4*>(&conv_b[q * 4]);
    float4 o;
    o.x = fmaxf(s.x * inv + cb.x, 0.f);
    o.y = fmaxf(s.y * inv + cb.y, 0.f);
    o.z = fmaxf(s.z * inv + cb.z, 0.f);
    o.w = fmaxf(s.w * inv + cb.w, 0.f);
    *reinterpret_cast<float4*>(&h[n * 32 + q * 4]) = o;
}

// ---- classifier: 32 edges per 256-thread block ----
__global__ __launch_bounds__(256) void classifier(
    const float* __restrict__ h, const float* __restrict__ ef,
    const int* __restrict__ src, const int* __restrict__ dst, const int* __restrict__ eidx,
    const float* __restrict__ w1, const float* __restrict__ b1,
    const float* __restrict__ w2, const float* __restrict__ b2, float* __restrict__ out)
{
    __shared__ float sIn[32][84];
    __shared__ float sW1[80 * 32];
    __shared__ float sHid[32][36];
    __shared__ int   sE[32 * 3];
    int tid = threadIdx.x;
    int eb  = blockIdx.x * 32;

    for (int i = tid; i < 640; i += 256)
        *reinterpret_cast<float4*>(&sW1[i * 4]) = *reinterpret_cast<const float4*>(&w1[i * 4]);
    if (tid < 32) {
        int ei = eidx[eb + tid];
        sE[tid * 3 + 0] = ei;
        sE[tid * 3 + 1] = src[ei];
        sE[tid * 3 + 2] = dst[ei];
    }
    __syncthreads();
    {
        int e = tid >> 3, l8 = tid & 7;
        int ei = sE[e * 3 + 0], sn = sE[e * 3 + 1], dn = sE[e * 3 + 2];
        #pragma unroll
        for (int j = 0; j < 10; ++j) {
            int c = l8 + j * 8;
            float v;
            if (c < 32)      v = h[sn * 32 + c];
            else if (c < 64) v = h[dn * 32 + (c - 32)];
            else             v = ef[ei * 16 + (c - 64)];
            sIn[e][c] = v;
        }
    }
    __syncthreads();
    {
        int e = tid >> 3, j0 = (tid & 7) * 4;
        float4 acc = *reinterpret_cast<const float4*>(&b1[j0]);
        #pragma unroll 8
        for (int k = 0; k < 80; ++k) {
            float x = sIn[e][k];
            float4 wv = *reinterpret_cast<const float4*>(&sW1[k * 32 + j0]);
            acc.x += x * wv.x; acc.y += x * wv.y; acc.z += x * wv.z; acc.w += x * wv.w;
        }
        sHid[e][j0 + 0] = fmaxf(acc.x, 0.f);
        sHid[e][j0 + 1] = fmaxf(acc.y, 0.f);
        sHid[e][j0 + 2] = fmaxf(acc.z, 0.f);
        sHid[e][j0 + 3] = fmaxf(acc.w, 0.f);
    }
    __syncthreads();
    if (tid < 64) {
        int e = tid >> 1, o = tid & 1;
        float acc = b2[o];
        #pragma unroll
        for (int j = 0; j < 32; ++j) acc += sHid[e][j] * w2[j * 2 + o];
        out[(eb + e) * 2 + o] = acc;
    }
}

extern "C" void kernel_launch(void* const* d_in, const int* in_sizes, int n_in,
                              void* d_out, int out_size, void* d_ws, size_t ws_size,
                              hipStream_t stream) {
    const float* nf     = (const float*)d_in[0];
    const float* ef     = (const float*)d_in[1];
    const int*   src    = (const int*)d_in[2];
    const int*   dst    = (const int*)d_in[3];
    const int*   eidx   = (const int*)d_in[4];
    const float* en_w1  = (const float*)d_in[5];
    const float* en_b1  = (const float*)d_in[6];
    const float* en_w2  = (const float*)d_in[7];
    const float* en_b2  = (const float*)d_in[8];
    const float* conv_b = (const float*)d_in[9];
    const float* cls_w1 = (const float*)d_in[10];
    const float* cls_b1 = (const float*)d_in[11];
    const float* cls_w2 = (const float*)d_in[12];
    const float* cls_b2 = (const float*)d_in[13];
    float* out = (float*)d_out;

    char* ws = (char*)d_ws;
    unsigned short* w2ts   = (unsigned short*)(ws);                 // 131,072 B (pre-swizzled, n&15 key)
    unsigned short* w1t    = (unsigned short*)(ws + 131072);        //   8,192 B
    int*            cursor = (int*)(ws + 139264);                   // 200,000 B
    int*            slots  = (int*)(ws + 339264);                   // 8,000,000 B
    float*          msgb   = (float*)(ws + 8339264);                // 51,200,000 B
    float*          h      = (float*)(ws + 59539264);               // 6,400,000 B

    hipMemsetAsync(cursor, 0, N_NODES * sizeof(int), stream);
    prep_and_slots<<<(N_EDGES + 255) / 256, 256, 0, stream>>>(en_w2, en_w1, dst, w2ts, w1t, cursor, slots);
    fused_msg<<<FUSED_BLOCKS, 256, 0, stream>>>(nf, ef, src, w1t, en_b1, w2ts, en_b2, msgb);
    aggregate_h<<<(N_NODES * 8 + 255) / 256, 256, 0, stream>>>(msgb, cursor, slots, conv_b, h);
    classifier<<<N_CLS / 32, 256, 0, stream>>>(h, ef, src, dst, eidx, cls_w1, cls_b1, cls_w2, cls_b2, out);
}